// Round 11
// baseline (219.712 us; speedup 1.0000x reference)
//
#include <hip/hip_runtime.h>

// Problem constants (B=2, T=2048, D=1024, N_EXP=8, TOP_K=2, CAP_FACTOR=1.25)
#define N_TOK   4096
#define DDIM    1024
#define N_EXP   8
#define CAP     1280                       // floor(2*1.25*4096/8), even, >=4
#define ROW     (N_EXP * CAP)              // 10240 floats per token row
#define CB_ELEMS (N_TOK * ROW)             // 41,943,040 floats per output tensor

// fill geometry: 512 blocks x 1024 thr; 640 KB contiguous chunk per block
#define FBLK        512
#define FTHR        1024
#define CHUNK_F32   163840                 // floats per block (= 16 token rows)
#define CHUNK4      (CHUNK_F32 / 4)        // 40960 f32x4
#define FITERS      (CHUNK4 / FTHR)        // 40 stores per thread
#define TOK_PER_BLK 16

typedef __attribute__((ext_vector_type(4))) float f32x4;

// ws layout:
//   [0,     4096)  : uint  pk[1024]   packed 4-bit expert ids, entry-major:
//                    entry i = k*4096 + t -> nibble (i&7) of word (i>>3)
//   [4096,  20480) : f32   p0[4096]   softmax weight, slot k=0
//   [20480, 36864) : f32   p1[4096]   softmax weight, slot k=1

// ---------------------------------------------------------------------------
// Kernel 1: router — 4096x8 GEMV, top-2, softmax over the 2 selected logits.
// One wave per token (4/block); packed nibble output. (R9-proven, unchanged)
// ---------------------------------------------------------------------------
__global__ __launch_bounds__(256) void router_kernel(
    const float* __restrict__ x, const float* __restrict__ wg,
    unsigned int* __restrict__ pk,
    float* __restrict__ p0, float* __restrict__ p1)
{
    __shared__ int se0[4], se1[4];
    const int wave = threadIdx.x >> 6;
    const int lane = threadIdx.x & 63;
    const int t = blockIdx.x * 4 + wave;

    const float4* xt  = (const float4*)(x + (size_t)t * DDIM);  // 256 float4
    const float4* wg4 = (const float4*)wg;                      // [8][256]

    float acc[N_EXP];
#pragma unroll
    for (int e = 0; e < N_EXP; ++e) acc[e] = 0.f;

#pragma unroll
    for (int it = 0; it < 4; ++it) {
        const int d4 = lane + it * 64;
        const float4 xv = xt[d4];
#pragma unroll
        for (int e = 0; e < N_EXP; ++e) {
            const float4 wv = wg4[e * 256 + d4];
            acc[e] = fmaf(xv.x, wv.x,
                     fmaf(xv.y, wv.y,
                     fmaf(xv.z, wv.z,
                     fmaf(xv.w, wv.w, acc[e]))));
        }
    }

#pragma unroll
    for (int e = 0; e < N_EXP; ++e) {
#pragma unroll
        for (int off = 32; off >= 1; off >>= 1)
            acc[e] += __shfl_xor(acc[e], off, 64);
    }

    if (lane == 0) {
        // stable top-2 (strict >) matches jax.lax.top_k tie-breaking
        float v0 = -3.402823466e38f, v1 = -3.402823466e38f;
        int   i0 = 0, i1 = 0;
#pragma unroll
        for (int e = 0; e < N_EXP; ++e) {
            const float v = acc[e];
            if (v > v0)      { v1 = v0; i1 = i0; v0 = v; i0 = e; }
            else if (v > v1) { v1 = v;  i1 = e; }
        }
        const float ex  = expf(v1 - v0);
        const float inv = 1.f / (1.f + ex);
        p0[t] = inv;        // softmax([v0,v1])[0]
        p1[t] = ex * inv;   // softmax([v0,v1])[1]
        se0[wave] = i0;
        se1[wave] = i1;
    }
    __syncthreads();

    if (threadIdx.x == 0) {
        const int b = blockIdx.x;
        unsigned short* pks = (unsigned short*)pk;
        const unsigned short h0 = (unsigned short)(se0[0] | (se0[1] << 4) |
                                                   (se0[2] << 8) | (se0[3] << 12));
        const unsigned short h1 = (unsigned short)(se1[0] | (se1[1] << 4) |
                                                   (se1[2] << 8) | (se1[3] << 12));
        pks[b]        = h0;   // k=0 entries 4b..4b+3
        pks[1024 + b] = h1;   // k=1 entries 4096+4b..4096+4b+3
    }
}

// ---------------------------------------------------------------------------
// Kernel 2: fill — 512 blocks x 1024 thr; ONE contiguous 640 KB stream per
// block (fewer, longer store streams -> DRAM row locality, rocclr-fill shape).
// Blocks [0,256): cb rows of tokens [16b,16b+16); [256,512): mask rows.
// pk is LDS-staged BEFORE the stores so the rank count (lgkmcnt-only)
// overlaps the store drain. 32 fixups/block after one final barrier.
// ---------------------------------------------------------------------------
__global__ __launch_bounds__(1024) void fill_kernel(
    const unsigned int* __restrict__ pk, const float* __restrict__ p0,
    const float* __restrict__ p1, float* __restrict__ out)
{
    __shared__ unsigned int spk[1024];   // 4 KB packed expert ids
    __shared__ int s_e[32], s_r[32];

    const int  b     = blockIdx.x;
    const bool is_cb = (b < FBLK / 2);
    const int  tbase = (is_cb ? b : (b - FBLK / 2)) * TOK_PER_BLK;

    // ---- stage pk first (1 load/thread; barrier waits only this) -----------
    spk[threadIdx.x] = pk[threadIdx.x];
    __syncthreads();

    // ---- issue the long zero-store stream (fire-and-forget) ----------------
    float* base = out + 8 + (size_t)b * CHUNK_F32;   // cb|mask contiguous
    f32x4* b4   = (f32x4*)base;
    const f32x4 z = {0.f, 0.f, 0.f, 0.f};
#pragma unroll
    for (int it = 0; it < FITERS; ++it)
        b4[threadIdx.x + it * FTHR] = z;             // 16 KB/iter contiguous

    // ---- rank recompute (LDS + VALU only; overlaps store drain) ------------
    const int wave = threadIdx.x >> 6;               // 0..15 -> token tbase+wave
    const int lane = threadIdx.x & 63;
    const int tt   = tbase + wave;

    unsigned int w[16];
#pragma unroll
    for (int j = 0; j < 16; ++j) w[j] = spk[lane + j * 64];  // 2-way bank: free

#pragma unroll
    for (int k = 0; k < 2; ++k) {                    // both slots of token tt
        const int i = k * N_TOK + tt;                // k-major entry index
        const int e = (int)((spk[i >> 3] >> ((i & 7) * 4)) & 0xF);
        int cnt = 0;
#pragma unroll
        for (int j = 0; j < 16; ++j) {
            const int bi = (lane + j * 64) * 8;      // entry idx of nibble 0
#pragma unroll
            for (int s = 0; s < 8; ++s)
                cnt += (bi + s < i && (int)((w[j] >> (4 * s)) & 0xF) == e) ? 1 : 0;
        }
#pragma unroll
        for (int off = 32; off >= 1; off >>= 1)
            cnt += __shfl_xor(cnt, off, 64);
        if (lane == 0) { s_e[wave * 2 + k] = e; s_r[wave * 2 + k] = cnt; }
    }

    // ---- block 0: used_capacity[8] (VALU on live regs, global write) -------
    if (b == 0 && wave < N_EXP) {
        int c = 0;
#pragma unroll
        for (int j = 0; j < 16; ++j) {
#pragma unroll
            for (int s = 0; s < 8; ++s)
                c += ((int)((w[j] >> (4 * s)) & 0xF) == wave) ? 1 : 0;
        }
#pragma unroll
        for (int off = 32; off >= 1; off >>= 1)
            c += __shfl_xor(c, off, 64);
        if (lane == 0) out[wave] = (float)min(c, CAP);
    }

    __syncthreads();   // drains stores (vmcnt 0); s_e/s_r visible

    // ---- fixups: 32 entries (16 tokens x 2 slots), L2-warm -----------------
    if (threadIdx.x < 32) {
        const int r = s_r[threadIdx.x];
        if (r < CAP) {                               // dropped tokens skipped
            const int   t2 = tbase + (threadIdx.x >> 1);
            const float wv = (threadIdx.x & 1) ? p1[t2] : p0[t2];
            const float v  = is_cb ? wv : ((wv != 0.f) ? 1.f : 0.f);
            base[(size_t)(threadIdx.x >> 1) * ROW
                 + (size_t)s_e[threadIdx.x] * CAP + r] = v;
        }
    }
}

// ---------------------------------------------------------------------------
extern "C" void kernel_launch(void* const* d_in, const int* in_sizes, int n_in,
                              void* d_out, int out_size, void* d_ws, size_t ws_size,
                              hipStream_t stream)
{
    const float* x  = (const float*)d_in[0];   // [2,2048,1024] f32
    const float* wg = (const float*)d_in[1];   // [8,1024] f32
    float* out = (float*)d_out;                // [8] used | cb | mask

    char*         ws = (char*)d_ws;
    unsigned int* pk = (unsigned int*)(ws);
    float*        p0 = (float*)(ws + 4096);
    float*        p1 = (float*)(ws + 20480);

    router_kernel<<<N_TOK / 4, 256, 0, stream>>>(x, wg, pk, p0, p1);
    fill_kernel<<<FBLK, FTHR, 0, stream>>>(pk, p0, p1, out);
}

// Round 12
// 120.534 us; speedup vs baseline: 1.8228x; 1.8228x over previous
//
#include <hip/hip_runtime.h>

// Problem constants (B=2, T=2048, D=1024, N_EXP=8, TOP_K=2, CAP_FACTOR=1.25)
#define N_TOK   4096
#define DDIM    1024
#define N_EXP   8
#define CAP     1280                       // floor(2*1.25*4096/8), even, >=4
#define ROW     (N_EXP * CAP)              // 10240 floats per token row
#define CB_ELEMS (N_TOK * ROW)             // 41,943,040 floats per output tensor
#define CHUNK   20480                      // floats per fill block (80 KB, line-aligned)

typedef __attribute__((ext_vector_type(4))) float f32x4;

// ws layout:
//   [0,     4096)  : uint  pk[1024]   packed 4-bit expert ids, entry-major:
//                    entry i = k*4096 + t -> nibble (i&7) of word (i>>3)
//   [4096,  20480) : f32   p0[4096]   softmax weight, slot k=0
//   [20480, 36864) : f32   p1[4096]   softmax weight, slot k=1

// ---------------------------------------------------------------------------
// Kernel 1: router — 4096x8 GEMV, top-2, softmax over the 2 selected logits.
// One wave per token (4/block); packed nibble output. (R9-proven, unchanged)
// ---------------------------------------------------------------------------
__global__ __launch_bounds__(256) void router_kernel(
    const float* __restrict__ x, const float* __restrict__ wg,
    unsigned int* __restrict__ pk,
    float* __restrict__ p0, float* __restrict__ p1)
{
    __shared__ int se0[4], se1[4];
    const int wave = threadIdx.x >> 6;
    const int lane = threadIdx.x & 63;
    const int t = blockIdx.x * 4 + wave;

    const float4* xt  = (const float4*)(x + (size_t)t * DDIM);  // 256 float4
    const float4* wg4 = (const float4*)wg;                      // [8][256]

    float acc[N_EXP];
#pragma unroll
    for (int e = 0; e < N_EXP; ++e) acc[e] = 0.f;

#pragma unroll
    for (int it = 0; it < 4; ++it) {
        const int d4 = lane + it * 64;
        const float4 xv = xt[d4];
#pragma unroll
        for (int e = 0; e < N_EXP; ++e) {
            const float4 wv = wg4[e * 256 + d4];
            acc[e] = fmaf(xv.x, wv.x,
                     fmaf(xv.y, wv.y,
                     fmaf(xv.z, wv.z,
                     fmaf(xv.w, wv.w, acc[e]))));
        }
    }

#pragma unroll
    for (int e = 0; e < N_EXP; ++e) {
#pragma unroll
        for (int off = 32; off >= 1; off >>= 1)
            acc[e] += __shfl_xor(acc[e], off, 64);
    }

    if (lane == 0) {
        // stable top-2 (strict >) matches jax.lax.top_k tie-breaking
        float v0 = -3.402823466e38f, v1 = -3.402823466e38f;
        int   i0 = 0, i1 = 0;
#pragma unroll
        for (int e = 0; e < N_EXP; ++e) {
            const float v = acc[e];
            if (v > v0)      { v1 = v0; i1 = i0; v0 = v; i0 = e; }
            else if (v > v1) { v1 = v;  i1 = e; }
        }
        const float ex  = expf(v1 - v0);
        const float inv = 1.f / (1.f + ex);
        p0[t] = inv;        // softmax([v0,v1])[0]
        p1[t] = ex * inv;   // softmax([v0,v1])[1]
        se0[wave] = i0;
        se1[wave] = i1;
    }
    __syncthreads();

    if (threadIdx.x == 0) {
        const int b = blockIdx.x;
        unsigned short* pks = (unsigned short*)pk;
        const unsigned short h0 = (unsigned short)(se0[0] | (se0[1] << 4) |
                                                   (se0[2] << 8) | (se0[3] << 12));
        const unsigned short h1 = (unsigned short)(se1[0] | (se1[1] << 4) |
                                                   (se1[2] << 8) | (se1[3] << 12));
        pks[b]        = h0;   // k=0 entries 4b..4b+3
        pks[1024 + b] = h1;   // k=1 entries 4096+4b..4096+4b+3
    }
}

// ---------------------------------------------------------------------------
// Kernel 2: fill — ALIGNED chunking. Block b zeroes the 128B-aligned float
// range [b*20480, (b+1)*20480) of the WHOLE output (header absorbed into
// block 0, 8-float tail into block 4095) -> every wave store covers full
// lines -> no write-miss RMW (R11 counters: misaligned fill fetched 144 MB).
// Fixups follow chunk ownership: candidates {2c-1, 2c, 2c+1} (+4095 for the
// cb/mask straddle at b==2048), bounds-checked into [lo, hi). Block 0 writes
// used_capacity after the barrier. Ranks recomputed from 4 KB pk (L2-hot).
// ---------------------------------------------------------------------------
__global__ __launch_bounds__(256) void fill_kernel(
    const unsigned int* __restrict__ pk, const float* __restrict__ p0,
    const float* __restrict__ p1, float* __restrict__ out)
{
    __shared__ unsigned int spk[1024];   // 4 KB packed expert ids
    __shared__ int s_e[8], s_r[8], s_used[8];

    const int b  = blockIdx.x;
    const int lo = b * CHUNK;            // global float index of chunk start

    // ---- aligned streaming zero stores (full-line coverage) ----------------
    f32x4* b4 = (f32x4*)out + (size_t)b * (CHUNK / 4);
    const f32x4 z = {0.f, 0.f, 0.f, 0.f};
#pragma unroll
    for (int it = 0; it < 20; ++it)
        b4[threadIdx.x + it * 256] = z;
    if (b == 4095 && threadIdx.x < 2)    // global 8-float tail (aligned)
        ((f32x4*)out)[(size_t)4096 * (CHUNK / 4) + threadIdx.x] = z;

    // ---- stage pk to LDS (R9-proven order: after store issue) --------------
#pragma unroll
    for (int j = 0; j < 4; ++j)
        spk[threadIdx.x + j * 256] = pk[threadIdx.x + j * 256];
    __syncthreads();

    const int wave = threadIdx.x >> 6;
    const int lane = threadIdx.x & 63;
    const int c    = b & 2047;           // pair index within cb / mask region
    const int t0   = 2 * c;
    const int tc   = (wave == 0) ? t0 - 1 : (wave == 1) ? t0 :
                     (wave == 2) ? t0 + 1 : ((b == 2048) ? N_TOK - 1 : -1);

    unsigned int w[16];
#pragma unroll
    for (int j = 0; j < 16; ++j) w[j] = spk[lane + j * 64];  // 2-way bank: free

    if (tc >= 0 && tc < N_TOK) {
#pragma unroll
        for (int k = 0; k < 2; ++k) {    // both slots of candidate token tc
            const int i = k * N_TOK + tc;                  // k-major entry idx
            const int e = (int)((spk[i >> 3] >> ((i & 7) * 4)) & 0xF);
            int cnt = 0;
#pragma unroll
            for (int j = 0; j < 16; ++j) {
                const int bi = (lane + j * 64) * 8;        // entry of nibble 0
#pragma unroll
                for (int s = 0; s < 8; ++s)
                    cnt += (bi + s < i &&
                            (int)((w[j] >> (4 * s)) & 0xF) == e) ? 1 : 0;
            }
#pragma unroll
            for (int off = 32; off >= 1; off >>= 1)
                cnt += __shfl_xor(cnt, off, 64);
            if (lane == 0) { s_e[wave * 2 + k] = e; s_r[wave * 2 + k] = cnt; }
        }
    } else if (lane == 0) {
        s_r[wave * 2] = 1 << 20; s_r[wave * 2 + 1] = 1 << 20;
        s_e[wave * 2] = 0;       s_e[wave * 2 + 1] = 0;
    }

    // ---- block 0: used_capacity counts (reuses live w[] regs) --------------
    if (b == 0) {
#pragma unroll
        for (int q = 0; q < 2; ++q) {
            const int ee = wave * 2 + q;
            int cu = 0;
#pragma unroll
            for (int j = 0; j < 16; ++j) {
#pragma unroll
                for (int s = 0; s < 8; ++s)
                    cu += ((int)((w[j] >> (4 * s)) & 0xF) == ee) ? 1 : 0;
            }
#pragma unroll
            for (int off = 32; off >= 1; off >>= 1)
                cu += __shfl_xor(cu, off, 64);
            if (lane == 0) s_used[ee] = min(cu, CAP);
        }
    }

    __syncthreads();   // zero stores drained; s_* visible

    // ---- fixups: 8 entries x {cb, mask}, only targets inside this chunk ----
    if (threadIdx.x < 16) {
        const int  q  = threadIdx.x >> 1;               // entry 0..7
        const bool mk = threadIdx.x & 1;                // 0: cb, 1: mask
        const int  r  = s_r[q];
        if (r < CAP) {                                  // dropped/invalid skip
            const int wv2 = q >> 1;
            const int k   = q & 1;
            const int tt  = (wv2 == 0) ? t0 - 1 : (wv2 == 1) ? t0 :
                            (wv2 == 2) ? t0 + 1 : N_TOK - 1;
            const int g   = 8 + tt * ROW + s_e[q] * CAP + r
                            + (mk ? CB_ELEMS : 0);
            const int hi  = lo + CHUNK + ((b == 4095) ? 8 : 0);
            if (g >= lo && g < hi) {
                const float wv = k ? p1[tt] : p0[tt];
                out[(size_t)g] = mk ? ((wv != 0.f) ? 1.f : 0.f) : wv;
            }
        }
    }

    // ---- block 0: overwrite header with used_capacity (warm, ordered) ------
    if (b == 0 && threadIdx.x < 8)
        out[threadIdx.x] = (float)s_used[threadIdx.x];
}

// ---------------------------------------------------------------------------
extern "C" void kernel_launch(void* const* d_in, const int* in_sizes, int n_in,
                              void* d_out, int out_size, void* d_ws, size_t ws_size,
                              hipStream_t stream)
{
    const float* x  = (const float*)d_in[0];   // [2,2048,1024] f32
    const float* wg = (const float*)d_in[1];   // [8,1024] f32
    float* out = (float*)d_out;                // [8] used | cb | mask

    char*         ws = (char*)d_ws;
    unsigned int* pk = (unsigned int*)(ws);
    float*        p0 = (float*)(ws + 4096);
    float*        p1 = (float*)(ws + 20480);

    router_kernel<<<N_TOK / 4, 256, 0, stream>>>(x, wg, pk, p0, p1);
    fill_kernel<<<4096, 256, 0, stream>>>(pk, p0, p1, out);
}

// Round 13
// 82.895 us; speedup vs baseline: 2.6505x; 1.4541x over previous
//
#include <hip/hip_runtime.h>

// Problem constants (B=2, T=2048, D=1024, N_EXP=8, TOP_K=2, CAP_FACTOR=1.25)
#define N_TOK   4096
#define DDIM    1024
#define N_EXP   8
#define CAP     1280                       // floor(2*1.25*4096/8), even, >=4
#define ROW     (N_EXP * CAP)              // 10240 floats per token row
#define CB_ELEMS (N_TOK * ROW)             // 41,943,040 floats per output tensor
// total output = 8 + 2*CB_ELEMS = 83,886,088 floats = 20,971,522 f32x4 exactly

typedef __attribute__((ext_vector_type(4))) float f32x4;

// ws layout:
//   [0,     4096)  : uint  pk[1024]   packed 4-bit expert ids, entry-major:
//                    entry i = k*4096 + t -> nibble (i&7) of word (i>>3)
//   [4096,  20480) : f32   p0[4096]   softmax weight, slot k=0
//   [20480, 36864) : f32   p1[4096]   softmax weight, slot k=1

// ---------------------------------------------------------------------------
// Kernel 1: router — 4096x8 GEMV, top-2, softmax over the 2 selected logits.
// One wave per token (4/block); packed nibble output. (R9-proven, unchanged)
// ---------------------------------------------------------------------------
__global__ __launch_bounds__(256) void router_kernel(
    const float* __restrict__ x, const float* __restrict__ wg,
    unsigned int* __restrict__ pk,
    float* __restrict__ p0, float* __restrict__ p1)
{
    __shared__ int se0[4], se1[4];
    const int wave = threadIdx.x >> 6;
    const int lane = threadIdx.x & 63;
    const int t = blockIdx.x * 4 + wave;

    const float4* xt  = (const float4*)(x + (size_t)t * DDIM);  // 256 float4
    const float4* wg4 = (const float4*)wg;                      // [8][256]

    float acc[N_EXP];
#pragma unroll
    for (int e = 0; e < N_EXP; ++e) acc[e] = 0.f;

#pragma unroll
    for (int it = 0; it < 4; ++it) {
        const int d4 = lane + it * 64;
        const float4 xv = xt[d4];
#pragma unroll
        for (int e = 0; e < N_EXP; ++e) {
            const float4 wv = wg4[e * 256 + d4];
            acc[e] = fmaf(xv.x, wv.x,
                     fmaf(xv.y, wv.y,
                     fmaf(xv.z, wv.z,
                     fmaf(xv.w, wv.w, acc[e]))));
        }
    }

#pragma unroll
    for (int e = 0; e < N_EXP; ++e) {
#pragma unroll
        for (int off = 32; off >= 1; off >>= 1)
            acc[e] += __shfl_xor(acc[e], off, 64);
    }

    if (lane == 0) {
        // stable top-2 (strict >) matches jax.lax.top_k tie-breaking
        float v0 = -3.402823466e38f, v1 = -3.402823466e38f;
        int   i0 = 0, i1 = 0;
#pragma unroll
        for (int e = 0; e < N_EXP; ++e) {
            const float v = acc[e];
            if (v > v0)      { v1 = v0; i1 = i0; v0 = v; i0 = e; }
            else if (v > v1) { v1 = v;  i1 = e; }
        }
        const float ex  = expf(v1 - v0);
        const float inv = 1.f / (1.f + ex);
        p0[t] = inv;        // softmax([v0,v1])[0]
        p1[t] = ex * inv;   // softmax([v0,v1])[1]
        se0[wave] = i0;
        se1[wave] = i1;
    }
    __syncthreads();

    if (threadIdx.x == 0) {
        const int b = blockIdx.x;
        unsigned short* pks = (unsigned short*)pk;
        const unsigned short h0 = (unsigned short)(se0[0] | (se0[1] << 4) |
                                                   (se0[2] << 8) | (se0[3] << 12));
        const unsigned short h1 = (unsigned short)(se1[0] | (se1[1] << 4) |
                                                   (se1[2] << 8) | (se1[3] << 12));
        pks[b]        = h0;   // k=0 entries 4b..4b+3
        pks[1024 + b] = h1;   // k=1 entries 4096+4b..4096+4b+3
    }
}

// ---------------------------------------------------------------------------
// Kernel 2: zero — EXACT rocclr fillBufferAligned shape: 256 blocks x 256 thr
// (~1 block/CU, ~3.4 waves/CU like the 10.8% occupancy rocclr shows),
// grid-stride 1 MB, pure f32x4 stores, minimal VGPR, covers the whole output
// from out[0] (aligned by construction; header zeroed then overwritten by K3).
// ---------------------------------------------------------------------------
__global__ __launch_bounds__(256) void zero_kernel(float* __restrict__ out)
{
    f32x4* dst = (f32x4*)out;
    const int gid = blockIdx.x * 256 + threadIdx.x;   // 0..65535
    const f32x4 z = {0.f, 0.f, 0.f, 0.f};
    size_t i = gid;
#pragma unroll 8
    for (int it = 0; it < 320; ++it) {                // 320*65536 = 20,971,520
        dst[i] = z;
        i += 65536;                                   // 1 MB grid stride
    }
    if (gid < 2)                                      // exact 2-f32x4 tail
        dst[(size_t)320 * 65536 + gid] = z;
}

// ---------------------------------------------------------------------------
// Kernel 3: fixup — 2048 blocks x 4 waves; wave w of block j owns k-major
// entry i = 4j + w. Rank via R9-proven nibble count from LDS-staged pk;
// <=2 scattered stores per entry (cb + mask). Block 0 adds used_capacity.
// Runs after zero_kernel -> kernel-boundary ordering; cold-line RMW ~2 MB.
// ---------------------------------------------------------------------------
__global__ __launch_bounds__(256) void fixup_kernel(
    const unsigned int* __restrict__ pk, const float* __restrict__ p0,
    const float* __restrict__ p1, float* __restrict__ out)
{
    __shared__ unsigned int spk[1024];   // 4 KB packed expert ids
#pragma unroll
    for (int j = 0; j < 4; ++j)
        spk[threadIdx.x + j * 256] = pk[threadIdx.x + j * 256];
    __syncthreads();

    const int wave = threadIdx.x >> 6;
    const int lane = threadIdx.x & 63;
    const int i    = blockIdx.x * 4 + wave;          // k-major entry, < 8192
    const int t    = i & (N_TOK - 1);
    const int k    = i >> 12;

    unsigned int w[16];
#pragma unroll
    for (int j = 0; j < 16; ++j) w[j] = spk[lane + j * 64];  // all 1024 words

    const int e = (int)((spk[i >> 3] >> ((i & 7) * 4)) & 0xF);
    int cnt = 0;
#pragma unroll
    for (int j = 0; j < 16; ++j) {
        const int bi = (lane + j * 64) * 8;          // entry idx of nibble 0
#pragma unroll
        for (int s = 0; s < 8; ++s)
            cnt += (bi + s < i && (int)((w[j] >> (4 * s)) & 0xF) == e) ? 1 : 0;
    }
#pragma unroll
    for (int off = 32; off >= 1; off >>= 1)
        cnt += __shfl_xor(cnt, off, 64);

    if (lane == 0 && cnt < CAP) {                    // dropped tokens skipped
        const float wv = k ? p1[t] : p0[t];
        float* cb = out + 8 + (size_t)t * ROW + (size_t)e * CAP + cnt;
        cb[0]        = wv;
        cb[CB_ELEMS] = (wv != 0.f) ? 1.f : 0.f;
    }

    // block 0: used_capacity[8] — wave handles experts 2*wave, 2*wave+1
    if (blockIdx.x == 0) {
#pragma unroll
        for (int q = 0; q < 2; ++q) {
            const int ee = wave * 2 + q;
            int c = 0;
#pragma unroll
            for (int j = 0; j < 16; ++j) {
#pragma unroll
                for (int s = 0; s < 8; ++s)
                    c += ((int)((w[j] >> (4 * s)) & 0xF) == ee) ? 1 : 0;
            }
#pragma unroll
            for (int off = 32; off >= 1; off >>= 1)
                c += __shfl_xor(c, off, 64);
            if (lane == 0) out[ee] = (float)min(c, CAP);
        }
    }
}

// ---------------------------------------------------------------------------
extern "C" void kernel_launch(void* const* d_in, const int* in_sizes, int n_in,
                              void* d_out, int out_size, void* d_ws, size_t ws_size,
                              hipStream_t stream)
{
    const float* x  = (const float*)d_in[0];   // [2,2048,1024] f32
    const float* wg = (const float*)d_in[1];   // [8,1024] f32
    float* out = (float*)d_out;                // [8] used | cb | mask

    char*         ws = (char*)d_ws;
    unsigned int* pk = (unsigned int*)(ws);
    float*        p0 = (float*)(ws + 4096);
    float*        p1 = (float*)(ws + 20480);

    router_kernel<<<N_TOK / 4, 256, 0, stream>>>(x, wg, pk, p0, p1);
    zero_kernel<<<256, 256, 0, stream>>>(out);
    fixup_kernel<<<2048, 256, 0, stream>>>(pk, p0, p1, out);
}